// Round 3
// baseline (345.465 us; speedup 1.0000x reference)
//
#include <hip/hip_runtime.h>
#include <hip/hip_bf16.h>

#define N_ROWS 4096
#define DIM    512
#define M_ROWS 8192
#define NTILE  64            // 8192 / 128 output tile rows
#define NBLK   2080          // NTILE*(NTILE+1)/2 triangular tile pairs
// exp(sim/0.1) = exp2(sim * 10*log2(e))
#define EXP_SCALE 14.4269504088896340736f

typedef unsigned short ushort_t;
typedef __attribute__((ext_vector_type(8))) short short8;
typedef __attribute__((ext_vector_type(4))) float f32x4;

// float -> bf16 bits, round-to-nearest-even (inputs are finite)
__device__ __forceinline__ ushort_t f2bf(float x) {
  unsigned int bits = __float_as_uint(x);
  unsigned int lsb = (bits >> 16) & 1u;
  bits += 0x7fffu + lsb;
  return (ushort_t)(bits >> 16);
}

__device__ __forceinline__ void store4bf(ushort_t* p, float4 v, float s) {
  union { ushort_t u[4]; uint2 d; } pk;
  pk.u[0] = f2bf(v.x * s);
  pk.u[1] = f2bf(v.y * s);
  pk.u[2] = f2bf(v.z * s);
  pk.u[3] = f2bf(v.w * s);
  *(uint2*)p = pk.d;
}

// ---------------------------------------------------------------------------
// Kernel 1: per-row L2 normalize (fp32 math), emit bf16 reps[8192][512] and
// exact fp32 positives pos[i] = dot(z_i, z_j). Also zero-inits denom/counter
// (ws is re-poisoned 0xAA before every timed call).
// ---------------------------------------------------------------------------
__global__ __launch_bounds__(256) void norm_kernel(
    const float* __restrict__ ei, const float* __restrict__ ej,
    ushort_t* __restrict__ reps, float* __restrict__ pos,
    float* __restrict__ denom, int* __restrict__ counter) {
  int tid = threadIdx.x;
  if (blockIdx.x < 32) denom[blockIdx.x * 256 + tid] = 0.0f;
  if (blockIdx.x == 32 && tid == 0) *counter = 0;

  int b = blockIdx.x * 4 + (tid >> 6);
  int lane = tid & 63;
  const float4* pi = (const float4*)(ei + (size_t)b * DIM);
  const float4* pj = (const float4*)(ej + (size_t)b * DIM);
  float4 a0 = pi[lane];
  float4 a1 = pi[lane + 64];
  float4 b0 = pj[lane];
  float4 b1 = pj[lane + 64];

  float si = a0.x*a0.x + a0.y*a0.y + a0.z*a0.z + a0.w*a0.w
           + a1.x*a1.x + a1.y*a1.y + a1.z*a1.z + a1.w*a1.w;
  float sj = b0.x*b0.x + b0.y*b0.y + b0.z*b0.z + b0.w*b0.w
           + b1.x*b1.x + b1.y*b1.y + b1.z*b1.z + b1.w*b1.w;
  float dp = a0.x*b0.x + a0.y*b0.y + a0.z*b0.z + a0.w*b0.w
           + a1.x*b1.x + a1.y*b1.y + a1.z*b1.z + a1.w*b1.w;

#pragma unroll
  for (int m = 32; m >= 1; m >>= 1) {
    si += __shfl_xor(si, m, 64);
    sj += __shfl_xor(sj, m, 64);
    dp += __shfl_xor(dp, m, 64);
  }
  float ii = 1.0f / fmaxf(sqrtf(si), 1e-12f);
  float ij = 1.0f / fmaxf(sqrtf(sj), 1e-12f);
  if (lane == 0) pos[b] = dp * ii * ij;

  ushort_t* ri = reps + (size_t)b * DIM;
  ushort_t* rj = reps + (size_t)(b + N_ROWS) * DIM;
  store4bf(ri + lane * 4,       a0, ii);
  store4bf(ri + 256 + lane * 4, a1, ii);
  store4bf(rj + lane * 4,       b0, ij);
  store4bf(rj + 256 + lane * 4, b1, ij);
}

// ---------------------------------------------------------------------------
// Kernel 2: fused sim-GEMM + exp + masked row/col reduction + (last block) loss.
// Triangular grid (2080 blocks), 128x128 tile, 4 waves x (4x4) 16x16x32 MFMA.
// NO LDS, NO barriers in the K-loop: A/B fragments are loaded straight from
// global (reps is L1/L2-resident; fragment loads are fully coalesced: 4 lanes
// cover each 64-B row segment). 1-deep register pipeline; compiler emits
// fine-grained vmcnt waits since nothing forces a drain.
// ---------------------------------------------------------------------------
__global__ __launch_bounds__(256) void sim_kernel(
    const ushort_t* __restrict__ reps, float* __restrict__ denom,
    const float* __restrict__ pos, float* __restrict__ out,
    int* __restrict__ counter) {
  // decode triangular pair (bi <= bj), bi,bj in [0,64)
  int t = blockIdx.x;
  int bi = (int)((129.0f - sqrtf((float)(16641 - 8 * t))) * 0.5f);
  while (bi * (129 - bi) / 2 > t) --bi;
  while ((bi + 1) * (128 - bi) / 2 <= t) ++bi;
  int bj = bi + (t - bi * (129 - bi) / 2);

  int tid  = threadIdx.x;
  int wave = tid >> 6, lane = tid & 63;
  int wr = wave >> 1, wc = wave & 1;
  int quad = lane >> 4, l15 = lane & 15;

  // fragment base pointers (short8 units): row stride = 64, tr stride = 1024
  const short8* gA = (const short8*)(reps + (size_t)(bi * 128 + wr * 64 + l15) * DIM) + quad;
  const short8* gB = (const short8*)(reps + (size_t)(bj * 128 + wc * 64 + l15) * DIM) + quad;

  f32x4 zero4 = {0.0f, 0.0f, 0.0f, 0.0f};
  f32x4 acc[4][4];
#pragma unroll
  for (int tr = 0; tr < 4; ++tr)
#pragma unroll
    for (int tc = 0; tc < 4; ++tc) acc[tr][tc] = zero4;

  short8 aE[4], bE[4], aO[4], bO[4];
#pragma unroll
  for (int x = 0; x < 4; ++x) {
    aE[x] = gA[x * 1024];
    bE[x] = gB[x * 1024];
  }

  // K-loop: 16 iters of 32, unrolled 2x with even/odd register buffers
#pragma unroll
  for (int k = 0; k < 16; k += 2) {
    if (k + 1 < 16) {
#pragma unroll
      for (int x = 0; x < 4; ++x) {
        aO[x] = gA[x * 1024 + (k + 1) * 4];
        bO[x] = gB[x * 1024 + (k + 1) * 4];
      }
    }
#pragma unroll
    for (int tr = 0; tr < 4; ++tr)
#pragma unroll
      for (int tc = 0; tc < 4; ++tc)
        acc[tr][tc] = __builtin_amdgcn_mfma_f32_16x16x32_bf16(
            aE[tr], bE[tc], acc[tr][tc], 0, 0, 0);
    if (k + 2 < 16) {
#pragma unroll
      for (int x = 0; x < 4; ++x) {
        aE[x] = gA[x * 1024 + (k + 2) * 4];
        bE[x] = gB[x * 1024 + (k + 2) * 4];
      }
    }
#pragma unroll
    for (int tr = 0; tr < 4; ++tr)
#pragma unroll
      for (int tc = 0; tc < 4; ++tc)
        acc[tr][tc] = __builtin_amdgcn_mfma_f32_16x16x32_bf16(
            aO[tr], bO[tc], acc[tr][tc], 0, 0, 0);
  }

  // epilogue: e = exp(sim/T), mask diagonal, row sums + (off-diag) col sums.
  // C layout: col = l15 (+ tc*16), row = quad*4 + r (+ tr*16)  [m89/m91]
  int rowg_base = bi * 128 + wr * 64;
  int colg_base = bj * 128 + wc * 64;

  f32x4 rsum[4];
  float csum[4] = {0.0f, 0.0f, 0.0f, 0.0f};
#pragma unroll
  for (int tr = 0; tr < 4; ++tr) rsum[tr] = zero4;

#pragma unroll
  for (int tr = 0; tr < 4; ++tr) {
    int rowg0 = rowg_base + tr * 16 + quad * 4;
#pragma unroll
    for (int tc = 0; tc < 4; ++tc) {
      int colg = colg_base + tc * 16 + l15;
      f32x4 a = acc[tr][tc];
      f32x4 e;
#pragma unroll
      for (int r = 0; r < 4; ++r) {
        float v = exp2f(a[r] * EXP_SCALE);
        e[r] = ((rowg0 + r) == colg) ? 0.0f : v;
      }
      rsum[tr] += e;
      csum[tc] += e[0] + e[1] + e[2] + e[3];
    }
  }

  // reduce row sums across the 16 lanes sharing `quad` (masks 1,2,4,8)
#pragma unroll
  for (int m = 1; m <= 8; m <<= 1)
#pragma unroll
    for (int tr = 0; tr < 4; ++tr)
#pragma unroll
      for (int r = 0; r < 4; ++r)
        rsum[tr][r] += __shfl_xor(rsum[tr][r], m, 64);

  if (l15 == 0) {
#pragma unroll
    for (int tr = 0; tr < 4; ++tr)
#pragma unroll
      for (int r = 0; r < 4; ++r)
        atomicAdd(&denom[rowg_base + tr * 16 + quad * 4 + r], rsum[tr][r]);
  }

  if (bi != bj) {
    // reduce col sums across quads (masks 16,32)
#pragma unroll
    for (int m = 16; m <= 32; m <<= 1)
#pragma unroll
      for (int tc = 0; tc < 4; ++tc)
        csum[tc] += __shfl_xor(csum[tc], m, 64);
    if (quad == 0) {
#pragma unroll
      for (int tc = 0; tc < 4; ++tc)
        atomicAdd(&denom[colg_base + tc * 16 + l15], csum[tc]);
    }
  }

  // --- fused loss: last block to finish reduces denom -> out[0] ---
  __shared__ int islast;
  __shared__ float red[4];
  __threadfence();
  __syncthreads();
  if (tid == 0) islast = (atomicAdd(counter, 1) == NBLK - 1);
  __syncthreads();
  if (islast) {
    float p = 0.0f;
    for (int r = tid; r < M_ROWS; r += 256) {
      // atomic read: denom was written via device-scope atomics (L2-bypassing);
      // a plain load could hit a stale per-XCD line.
      float v = atomicAdd(&denom[r], 0.0f);
      p += logf(v) - pos[r & (N_ROWS - 1)] * 10.0f;
    }
#pragma unroll
    for (int m = 32; m >= 1; m >>= 1) p += __shfl_xor(p, m, 64);
    if ((tid & 63) == 0) red[tid >> 6] = p;
    __syncthreads();
    if (tid == 0)
      out[0] = (red[0] + red[1] + red[2] + red[3]) * (1.0f / M_ROWS);
  }
}

extern "C" void kernel_launch(void* const* d_in, const int* in_sizes, int n_in,
                              void* d_out, int out_size, void* d_ws, size_t ws_size,
                              hipStream_t stream) {
  const float* ei = (const float*)d_in[0];
  const float* ej = (const float*)d_in[1];
  float* out = (float*)d_out;

  char* ws = (char*)d_ws;
  ushort_t* reps = (ushort_t*)ws;                                     // 8 MB bf16
  float* denom = (float*)(ws + (size_t)M_ROWS * DIM * 2);             // 32 KB
  float* pos = (float*)(ws + (size_t)M_ROWS * DIM * 2 + M_ROWS * 4);  // 16 KB
  int* counter = (int*)(ws + (size_t)M_ROWS * DIM * 2 + M_ROWS * 4 + N_ROWS * 4);

  norm_kernel<<<N_ROWS / 4, 256, 0, stream>>>(ei, ej, reps, pos, denom, counter);
  sim_kernel<<<NBLK, 256, 0, stream>>>(reps, denom, pos, out, counter);
}

// Round 4
// 321.799 us; speedup vs baseline: 1.0735x; 1.0735x over previous
//
#include <hip/hip_runtime.h>
#include <hip/hip_bf16.h>

#define N_ROWS 4096
#define DIM    512
#define M_ROWS 8192
#define BK     32
#define NITER  (DIM / BK)      // 16
#define TILE_E (128 * BK)      // shorts per stage tile (8 KB)
#define NLIVE  2080            // live (bi<=bj) blocks
// exp(sim/0.1) = exp2(sim * 10*log2(e))
#define EXP_SCALE 14.4269504088896340736f

typedef unsigned short ushort_t;
typedef __attribute__((ext_vector_type(8))) short short8;
typedef __attribute__((ext_vector_type(4))) float f32x4;

// float -> bf16 bits, round-to-nearest-even (inputs are finite)
__device__ __forceinline__ ushort_t f2bf(float x) {
  unsigned int bits = __float_as_uint(x);
  unsigned int lsb = (bits >> 16) & 1u;
  bits += 0x7fffu + lsb;
  return (ushort_t)(bits >> 16);
}

__device__ __forceinline__ void store4bf(ushort_t* p, float4 v, float s) {
  union { ushort_t u[4]; uint2 d; } pk;
  pk.u[0] = f2bf(v.x * s);
  pk.u[1] = f2bf(v.y * s);
  pk.u[2] = f2bf(v.z * s);
  pk.u[3] = f2bf(v.w * s);
  *(uint2*)p = pk.d;
}

// async global -> LDS, 16 bytes per lane (lds dest = wave-uniform base + lane*16)
__device__ __forceinline__ void async16(const ushort_t* g, ushort_t* l) {
  __builtin_amdgcn_global_load_lds(
      (const __attribute__((address_space(1))) void*)g,
      (__attribute__((address_space(3))) void*)l,
      16, 0, 0);
}

// ---------------------------------------------------------------------------
// Kernel 1: per-row L2 normalize (fp32 math), emit bf16 reps[8192][512] and
// exact fp32 positives pos[i] = dot(z_i, z_j). Also zero-inits denom/counter
// (ws is re-poisoned 0xAA before every timed call).
// ---------------------------------------------------------------------------
__global__ __launch_bounds__(256) void norm_kernel(
    const float* __restrict__ ei, const float* __restrict__ ej,
    ushort_t* __restrict__ reps, float* __restrict__ pos,
    float* __restrict__ denom, int* __restrict__ counter) {
  int tid = threadIdx.x;
  if (blockIdx.x < 32) denom[blockIdx.x * 256 + tid] = 0.0f;
  if (blockIdx.x == 32 && tid == 0) *counter = 0;

  int b = blockIdx.x * 4 + (tid >> 6);
  int lane = tid & 63;
  const float4* pi = (const float4*)(ei + (size_t)b * DIM);
  const float4* pj = (const float4*)(ej + (size_t)b * DIM);
  float4 a0 = pi[lane];
  float4 a1 = pi[lane + 64];
  float4 b0 = pj[lane];
  float4 b1 = pj[lane + 64];

  float si = a0.x*a0.x + a0.y*a0.y + a0.z*a0.z + a0.w*a0.w
           + a1.x*a1.x + a1.y*a1.y + a1.z*a1.z + a1.w*a1.w;
  float sj = b0.x*b0.x + b0.y*b0.y + b0.z*b0.z + b0.w*b0.w
           + b1.x*b1.x + b1.y*b1.y + b1.z*b1.z + b1.w*b1.w;
  float dp = a0.x*b0.x + a0.y*b0.y + a0.z*b0.z + a0.w*b0.w
           + a1.x*b1.x + a1.y*b1.y + a1.z*b1.z + a1.w*b1.w;

#pragma unroll
  for (int m = 32; m >= 1; m >>= 1) {
    si += __shfl_xor(si, m, 64);
    sj += __shfl_xor(sj, m, 64);
    dp += __shfl_xor(dp, m, 64);
  }
  float ii = 1.0f / fmaxf(sqrtf(si), 1e-12f);
  float ij = 1.0f / fmaxf(sqrtf(sj), 1e-12f);
  if (lane == 0) pos[b] = dp * ii * ij;

  ushort_t* ri = reps + (size_t)b * DIM;
  ushort_t* rj = reps + (size_t)(b + N_ROWS) * DIM;
  store4bf(ri + lane * 4,       a0, ii);
  store4bf(ri + 256 + lane * 4, a1, ii);
  store4bf(rj + lane * 4,       b0, ij);
  store4bf(rj + 256 + lane * 4, b1, ij);
}

// ---------------------------------------------------------------------------
// Kernel 2: fused sim-GEMM + exp + masked row/col reduction + (last block) loss.
// 2D grid (L2-friendly dispatch order; bi>bj blocks exit immediately).
// 128x128 tile, 4 waves x (4x4) 16x16x32 MFMA.
// Double-buffered LDS, ONE barrier per K-iter; prefetch for k+1 is issued
// after the barrier so the barrier's vmcnt(0) drain covers loads that have
// had a full iteration (MFMA+ds_read) in flight.
// ---------------------------------------------------------------------------
__global__ __launch_bounds__(256) void sim_kernel(
    const ushort_t* __restrict__ reps, float* __restrict__ denom,
    const float* __restrict__ pos, float* __restrict__ out,
    int* __restrict__ counter) {
  int bj = blockIdx.x, bi = blockIdx.y;
  if (bi > bj) return;

  __shared__ ushort_t As[2][TILE_E];
  __shared__ ushort_t Bs[2][TILE_E];

  int tid  = threadIdx.x;
  int wave = tid >> 6, lane = tid & 63;
  int wr = wave >> 1, wc = wave & 1;
  int quad = lane >> 4, l15 = lane & 15;

  // staging: chunk c (16 rows) = LDS shorts [c*512, c*512+512)
  int c0 = wave * 2, c1 = c0 + 1;
  int srow  = lane >> 2;
  int selem = (lane & 3) * 8;
  const ushort_t* gA0 = reps + (size_t)(bi * 128 + c0 * 16 + srow) * DIM + selem;
  const ushort_t* gA1 = reps + (size_t)(bi * 128 + c1 * 16 + srow) * DIM + selem;
  const ushort_t* gB0 = reps + (size_t)(bj * 128 + c0 * 16 + srow) * DIM + selem;
  const ushort_t* gB1 = reps + (size_t)(bj * 128 + c1 * 16 + srow) * DIM + selem;
  int c0o = c0 * 512, c1o = c1 * 512;

  f32x4 zero4 = {0.0f, 0.0f, 0.0f, 0.0f};
  f32x4 acc[4][4];
#pragma unroll
  for (int tr = 0; tr < 4; ++tr)
#pragma unroll
    for (int tc = 0; tc < 4; ++tc) acc[tr][tc] = zero4;

  // prologue: stage 0 into buffer 0
  async16(gA0, &As[0][c0o]);
  async16(gA1, &As[0][c1o]);
  async16(gB0, &Bs[0][c0o]);
  async16(gB1, &Bs[0][c1o]);

  for (int k = 0; k < NITER; ++k) {
    __syncthreads();  // stage k visible; prior readers of the alt buffer done
    if (k + 1 < NITER) {
      int off = (k + 1) * BK;
      int nb = (k + 1) & 1;
      async16(gA0 + off, &As[nb][c0o]);
      async16(gA1 + off, &As[nb][c1o]);
      async16(gB0 + off, &Bs[nb][c0o]);
      async16(gB1 + off, &Bs[nb][c1o]);
    }
    int cb = k & 1;
    short8 aF[4], bF[4];
#pragma unroll
    for (int tt = 0; tt < 4; ++tt) {
      aF[tt] = *(const short8*)(&As[cb][(wr * 64 + tt * 16 + l15) * BK + quad * 8]);
      bF[tt] = *(const short8*)(&Bs[cb][(wc * 64 + tt * 16 + l15) * BK + quad * 8]);
    }
#pragma unroll
    for (int tr = 0; tr < 4; ++tr)
#pragma unroll
      for (int tc = 0; tc < 4; ++tc)
        acc[tr][tc] = __builtin_amdgcn_mfma_f32_16x16x32_bf16(
            aF[tr], bF[tc], acc[tr][tc], 0, 0, 0);
  }

  // epilogue: e = exp(sim/T), mask diagonal, row sums + (off-diag) col sums.
  // C layout: col = l15 (+ tc*16), row = quad*4 + r (+ tr*16)  [m89/m91]
  int rowg_base = bi * 128 + wr * 64;
  int colg_base = bj * 128 + wc * 64;

  f32x4 rsum[4];
  float csum[4] = {0.0f, 0.0f, 0.0f, 0.0f};
#pragma unroll
  for (int tr = 0; tr < 4; ++tr) rsum[tr] = zero4;

#pragma unroll
  for (int tr = 0; tr < 4; ++tr) {
    int rowg0 = rowg_base + tr * 16 + quad * 4;
#pragma unroll
    for (int tc = 0; tc < 4; ++tc) {
      int colg = colg_base + tc * 16 + l15;
      f32x4 a = acc[tr][tc];
      f32x4 e;
#pragma unroll
      for (int r = 0; r < 4; ++r) {
        float v = exp2f(a[r] * EXP_SCALE);
        e[r] = ((rowg0 + r) == colg) ? 0.0f : v;
      }
      rsum[tr] += e;
      csum[tc] += e[0] + e[1] + e[2] + e[3];
    }
  }

  // reduce row sums across the 16 lanes sharing `quad` (masks 1,2,4,8)
#pragma unroll
  for (int m = 1; m <= 8; m <<= 1)
#pragma unroll
    for (int tr = 0; tr < 4; ++tr)
#pragma unroll
      for (int r = 0; r < 4; ++r)
        rsum[tr][r] += __shfl_xor(rsum[tr][r], m, 64);

  if (l15 == 0) {
#pragma unroll
    for (int tr = 0; tr < 4; ++tr)
#pragma unroll
      for (int r = 0; r < 4; ++r)
        atomicAdd(&denom[rowg_base + tr * 16 + quad * 4 + r], rsum[tr][r]);
  }

  if (bi != bj) {
    // reduce col sums across quads (masks 16,32)
#pragma unroll
    for (int m = 16; m <= 32; m <<= 1)
#pragma unroll
      for (int tc = 0; tc < 4; ++tc)
        csum[tc] += __shfl_xor(csum[tc], m, 64);
    if (quad == 0) {
#pragma unroll
      for (int tc = 0; tc < 4; ++tc)
        atomicAdd(&denom[colg_base + tc * 16 + l15], csum[tc]);
    }
  }

  // --- fused loss: last live block to finish reduces denom -> out[0] ---
  __shared__ int islast;
  __shared__ float red[4];
  __threadfence();
  __syncthreads();
  if (tid == 0) islast = (atomicAdd(counter, 1) == NLIVE - 1);
  __syncthreads();
  if (islast) {
    float p = 0.0f;
    for (int r = tid; r < M_ROWS; r += 256) {
      // atomic read: denom was written via device-scope atomics; a plain load
      // could hit a stale per-XCD line.
      float v = atomicAdd(&denom[r], 0.0f);
      p += logf(v) - pos[r & (N_ROWS - 1)] * 10.0f;
    }
#pragma unroll
    for (int m = 32; m >= 1; m >>= 1) p += __shfl_xor(p, m, 64);
    if ((tid & 63) == 0) red[tid >> 6] = p;
    __syncthreads();
    if (tid == 0)
      out[0] = (red[0] + red[1] + red[2] + red[3]) * (1.0f / M_ROWS);
  }
}

extern "C" void kernel_launch(void* const* d_in, const int* in_sizes, int n_in,
                              void* d_out, int out_size, void* d_ws, size_t ws_size,
                              hipStream_t stream) {
  const float* ei = (const float*)d_in[0];
  const float* ej = (const float*)d_in[1];
  float* out = (float*)d_out;

  char* ws = (char*)d_ws;
  ushort_t* reps = (ushort_t*)ws;                                     // 8 MB bf16
  float* denom = (float*)(ws + (size_t)M_ROWS * DIM * 2);             // 32 KB
  float* pos = (float*)(ws + (size_t)M_ROWS * DIM * 2 + M_ROWS * 4);  // 16 KB
  int* counter = (int*)(ws + (size_t)M_ROWS * DIM * 2 + M_ROWS * 4 + N_ROWS * 4);

  norm_kernel<<<N_ROWS / 4, 256, 0, stream>>>(ei, ej, reps, pos, denom, counter);
  sim_kernel<<<dim3(64, 64), 256, 0, stream>>>(reps, denom, pos, out, counter);
}

// Round 6
// 177.005 us; speedup vs baseline: 1.9517x; 1.8180x over previous
//
#include <hip/hip_runtime.h>
#include <hip/hip_bf16.h>

#define N_ROWS 4096
#define DIM    512
#define M_ROWS 8192
#define BK     64
#define NITER  (DIM / BK)      // 8
#define TILE_E (128 * BK)      // shorts per 128xBK tile (16 KB)
// exp(sim/0.1) = exp2(sim * 10*log2(e))
#define EXP_SCALE 14.4269504088896340736f

typedef unsigned short ushort_t;
typedef __attribute__((ext_vector_type(8))) short short8;
typedef __attribute__((ext_vector_type(4))) float f32x4;

// float -> bf16 bits, round-to-nearest-even (inputs are finite)
__device__ __forceinline__ ushort_t f2bf(float x) {
  unsigned int bits = __float_as_uint(x);
  unsigned int lsb = (bits >> 16) & 1u;
  bits += 0x7fffu + lsb;
  return (ushort_t)(bits >> 16);
}

__device__ __forceinline__ void store4bf(ushort_t* p, float4 v, float s) {
  union { ushort_t u[4]; uint2 d; } pk;
  pk.u[0] = f2bf(v.x * s);
  pk.u[1] = f2bf(v.y * s);
  pk.u[2] = f2bf(v.z * s);
  pk.u[3] = f2bf(v.w * s);
  *(uint2*)p = pk.d;
}

// async global -> LDS, 16 bytes per lane (lds dest = wave-uniform base + lane*16)
__device__ __forceinline__ void async16(const ushort_t* g, ushort_t* l) {
  __builtin_amdgcn_global_load_lds(
      (const __attribute__((address_space(1))) void*)g,
      (__attribute__((address_space(3))) void*)l,
      16, 0, 0);
}

// ---------------------------------------------------------------------------
// Kernel 1: per-row L2 normalize (fp32 math), emit bf16 reps[8192][512] and
// exact fp32 positives pos[i] = dot(z_i, z_j). Also zero-inits denom
// (ws is re-poisoned 0xAA before every timed call). No memset dispatch needed.
// ---------------------------------------------------------------------------
__global__ __launch_bounds__(256) void norm_kernel(
    const float* __restrict__ ei, const float* __restrict__ ej,
    ushort_t* __restrict__ reps, float* __restrict__ pos,
    float* __restrict__ denom) {
  int tid = threadIdx.x;
  if (blockIdx.x < 32) denom[blockIdx.x * 256 + tid] = 0.0f;

  int b = blockIdx.x * 4 + (tid >> 6);
  int lane = tid & 63;
  const float4* pi = (const float4*)(ei + (size_t)b * DIM);
  const float4* pj = (const float4*)(ej + (size_t)b * DIM);
  float4 a0 = pi[lane];
  float4 a1 = pi[lane + 64];
  float4 b0 = pj[lane];
  float4 b1 = pj[lane + 64];

  float si = a0.x*a0.x + a0.y*a0.y + a0.z*a0.z + a0.w*a0.w
           + a1.x*a1.x + a1.y*a1.y + a1.z*a1.z + a1.w*a1.w;
  float sj = b0.x*b0.x + b0.y*b0.y + b0.z*b0.z + b0.w*b0.w
           + b1.x*b1.x + b1.y*b1.y + b1.z*b1.z + b1.w*b1.w;
  float dp = a0.x*b0.x + a0.y*b0.y + a0.z*b0.z + a0.w*b0.w
           + a1.x*b1.x + a1.y*b1.y + a1.z*b1.z + a1.w*b1.w;

#pragma unroll
  for (int m = 32; m >= 1; m >>= 1) {
    si += __shfl_xor(si, m, 64);
    sj += __shfl_xor(sj, m, 64);
    dp += __shfl_xor(dp, m, 64);
  }
  float ii = 1.0f / fmaxf(sqrtf(si), 1e-12f);
  float ij = 1.0f / fmaxf(sqrtf(sj), 1e-12f);
  if (lane == 0) pos[b] = dp * ii * ij;

  ushort_t* ri = reps + (size_t)b * DIM;
  ushort_t* rj = reps + (size_t)(b + N_ROWS) * DIM;
  store4bf(ri + lane * 4,       a0, ii);
  store4bf(ri + 256 + lane * 4, a1, ii);
  store4bf(rj + lane * 4,       b0, ij);
  store4bf(rj + 256 + lane * 4, b1, ij);
}

// ---------------------------------------------------------------------------
// Kernel 2: fused sim-GEMM + exp + masked row/col reduction.
// 2D grid (proven L2-friendly order; bi>bj blocks exit immediately).
// 128x128 tile, 4 waves x (4x4) 16x16x32 MFMA, BK=64 single-buffered:
// 8 K-iters x 2 barriers (half the barrier-drain count of the BK=32 version),
// 32 MFMA/wave between drains. Fragments loaded per-K-half to cap VGPR.
// ---------------------------------------------------------------------------
__global__ __launch_bounds__(256) void sim_kernel(
    const ushort_t* __restrict__ reps, float* __restrict__ denom) {
  int bj = blockIdx.x, bi = blockIdx.y;
  if (bi > bj) return;

  __shared__ ushort_t As[TILE_E];
  __shared__ ushort_t Bs[TILE_E];

  int tid  = threadIdx.x;
  int wave = tid >> 6, lane = tid & 63;
  int wr = wave >> 1, wc = wave & 1;
  int quad = lane >> 4, l15 = lane & 15;

  // staging: chunk c in [0,16) = tile rows c*8..c*8+7, LDS shorts [c*512,(c+1)*512)
  // wave w stages chunks w*4..w*4+3 for both A and B.
  // lane: srow = lane>>3 (8 lanes x 16 B = one 128 B row), selem = (lane&7)*8
  int srow  = lane >> 3;
  int selem = (lane & 7) * 8;
  const ushort_t* gA[4];
  const ushort_t* gB[4];
  ushort_t* lA[4];
  ushort_t* lB[4];
#pragma unroll
  for (int i = 0; i < 4; ++i) {
    int c = wave * 4 + i;
    gA[i] = reps + (size_t)(bi * 128 + c * 8 + srow) * DIM + selem;
    gB[i] = reps + (size_t)(bj * 128 + c * 8 + srow) * DIM + selem;
    lA[i] = As + c * 512;
    lB[i] = Bs + c * 512;
  }

  f32x4 zero4 = {0.0f, 0.0f, 0.0f, 0.0f};
  f32x4 acc[4][4];
#pragma unroll
  for (int tr = 0; tr < 4; ++tr)
#pragma unroll
    for (int tc = 0; tc < 4; ++tc) acc[tr][tc] = zero4;

  for (int kk = 0; kk < DIM; kk += BK) {
    __syncthreads();  // prior iter's ds_reads done before overwrite
#pragma unroll
    for (int i = 0; i < 4; ++i) {
      async16(gA[i] + kk, lA[i]);
      async16(gB[i] + kk, lB[i]);
    }
    __syncthreads();  // staged tile visible (vmcnt drain)

#pragma unroll
    for (int h = 0; h < 2; ++h) {
      short8 aF[4], bF[4];
#pragma unroll
      for (int tt = 0; tt < 4; ++tt) {
        aF[tt] = *(const short8*)(&As[(wr * 64 + tt * 16 + l15) * BK + h * 32 + quad * 8]);
        bF[tt] = *(const short8*)(&Bs[(wc * 64 + tt * 16 + l15) * BK + h * 32 + quad * 8]);
      }
#pragma unroll
      for (int tr = 0; tr < 4; ++tr)
#pragma unroll
        for (int tc = 0; tc < 4; ++tc)
          acc[tr][tc] = __builtin_amdgcn_mfma_f32_16x16x32_bf16(
              aF[tr], bF[tc], acc[tr][tc], 0, 0, 0);
    }
  }

  // epilogue: e = exp(sim/T), mask diagonal, row sums + (off-diag) col sums.
  // C layout: col = l15 (+ tc*16), row = quad*4 + r (+ tr*16)  [m89/m91]
  int rowg_base = bi * 128 + wr * 64;
  int colg_base = bj * 128 + wc * 64;

  f32x4 rsum[4];
  float csum[4] = {0.0f, 0.0f, 0.0f, 0.0f};
#pragma unroll
  for (int tr = 0; tr < 4; ++tr) rsum[tr] = zero4;

#pragma unroll
  for (int tr = 0; tr < 4; ++tr) {
    int rowg0 = rowg_base + tr * 16 + quad * 4;
#pragma unroll
    for (int tc = 0; tc < 4; ++tc) {
      int colg = colg_base + tc * 16 + l15;
      f32x4 a = acc[tr][tc];
      f32x4 e;
#pragma unroll
      for (int r = 0; r < 4; ++r) {
        float v = exp2f(a[r] * EXP_SCALE);
        e[r] = ((rowg0 + r) == colg) ? 0.0f : v;
      }
      rsum[tr] += e;
      csum[tc] += e[0] + e[1] + e[2] + e[3];
    }
  }

  // reduce row sums across the 16 lanes sharing `quad` (masks 1,2,4,8)
#pragma unroll
  for (int m = 1; m <= 8; m <<= 1)
#pragma unroll
    for (int tr = 0; tr < 4; ++tr)
#pragma unroll
      for (int r = 0; r < 4; ++r)
        rsum[tr][r] += __shfl_xor(rsum[tr][r], m, 64);

  if (l15 == 0) {
#pragma unroll
    for (int tr = 0; tr < 4; ++tr)
#pragma unroll
      for (int r = 0; r < 4; ++r)
        atomicAdd(&denom[rowg_base + tr * 16 + quad * 4 + r], rsum[tr][r]);
  }

  if (bi != bj) {
    // reduce col sums across quads (masks 16,32)
#pragma unroll
    for (int m = 16; m <= 32; m <<= 1)
#pragma unroll
      for (int tc = 0; tc < 4; ++tc)
        csum[tc] += __shfl_xor(csum[tc], m, 64);
    if (quad == 0) {
#pragma unroll
      for (int tc = 0; tc < 4; ++tc)
        atomicAdd(&denom[colg_base + tc * 16 + l15], csum[tc]);
    }
  }
}

// ---------------------------------------------------------------------------
// Kernel 3: loss = mean over rows of [log(denom) - pos/T]
// (separate dispatch: the kernel boundary is the grid-wide sync; no fences)
// ---------------------------------------------------------------------------
__global__ __launch_bounds__(1024) void loss_kernel(
    const float* __restrict__ denom, const float* __restrict__ pos,
    float* __restrict__ out) {
  __shared__ float red[16];
  int tid = threadIdx.x;
  float p = 0.0f;
  for (int r = tid; r < M_ROWS; r += 1024)
    p += logf(denom[r]) - pos[r & (N_ROWS - 1)] * 10.0f;
#pragma unroll
  for (int m = 32; m >= 1; m >>= 1) p += __shfl_xor(p, m, 64);
  if ((tid & 63) == 0) red[tid >> 6] = p;
  __syncthreads();
  if (tid == 0) {
    float s = 0.0f;
#pragma unroll
    for (int w = 0; w < 16; ++w) s += red[w];
    out[0] = s * (1.0f / M_ROWS);
  }
}

extern "C" void kernel_launch(void* const* d_in, const int* in_sizes, int n_in,
                              void* d_out, int out_size, void* d_ws, size_t ws_size,
                              hipStream_t stream) {
  const float* ei = (const float*)d_in[0];
  const float* ej = (const float*)d_in[1];
  float* out = (float*)d_out;

  char* ws = (char*)d_ws;
  ushort_t* reps = (ushort_t*)ws;                                     // 8 MB bf16
  float* denom = (float*)(ws + (size_t)M_ROWS * DIM * 2);             // 32 KB
  float* pos = (float*)(ws + (size_t)M_ROWS * DIM * 2 + M_ROWS * 4);  // 16 KB

  norm_kernel<<<N_ROWS / 4, 256, 0, stream>>>(ei, ej, reps, pos, denom);
  sim_kernel<<<dim3(64, 64), 256, 0, stream>>>(reps, denom);
  loss_kernel<<<1, 1024, 0, stream>>>(denom, pos, out);
}